// Round 6
// baseline (524.733 us; speedup 1.0000x reference)
//
#include <hip/hip_runtime.h>

#define CC 128
#define HH 128
#define WW 128
#define DH 64
#define DW 64
#define LTOT 4096          // DH*DW patches / fg positions
#define K0S 384            // 3*128 split-concat K for the pixel-pair GEMM
#define K2 2048            // CC*4*4
#define GK 4096            // GEMM2 full K
#define GKH 2048           // GEMM2 half K (split-K by 2)
#define SCALE_F 10.0f
#define IMG ((size_t)CC * HH * WW)
#define PSTR 4104          // padded S row stride (floats): 4 pad | 4096 | 4 pad; %4==0 keeps 16B align

typedef __attribute__((ext_vector_type(8))) short short8;
typedef __attribute__((ext_vector_type(4))) float f32x4;

// ---- pointer-pack structs (batch-merged prep via blockIdx.z) ----
struct Prep4 { const float* src[4]; unsigned short* dst[4]; float* ssq[4]; int lo[4]; };
struct PtrN2 { const float* ssq[2]; float* invn[2]; float* mmv[2]; };
struct PtrR2 { const float* src[2]; unsigned short* dst[2]; };

// ---- bf16 helpers (RNE) ----
__device__ __forceinline__ unsigned short f2bf(float x) {
    union { float f; unsigned u; } v; v.f = x;
    unsigned r = v.u + 0x7fffu + ((v.u >> 16) & 1u);
    return (unsigned short)(r >> 16);
}
__device__ __forceinline__ float bf2f(unsigned short b) {
    union { unsigned u; float f; } v; v.u = ((unsigned)b) << 16;
    return v.f;
}

// unaligned (4B-aligned) float4 load
__device__ __forceinline__ f32x4 ld4u(const float* p) {
    f32x4 r; __builtin_memcpy(&r, p, 16); return r;
}

#define GLDS16(g, l) __builtin_amdgcn_global_load_lds( \
    (const __attribute__((address_space(1))) void*)(g), \
    (__attribute__((address_space(3))) void*)(l), 16, 0, 0)

// ---------------- downsample (::2) + fp32->bf16 split + (for b) fused ssq reduce ----------------
// b gets [hi, lo, hi], f gets [hi, hi, lo]  =>  products sum to hi*hi + lo*hi + hi*lo
__global__ __launch_bounds__(128) void split_ds_kernel(Prep4 P) {
    __shared__ float partial[2];
    int z = blockIdx.z;
    const float* __restrict__ src = P.src[z];
    unsigned short* __restrict__ dst = P.dst[z];
    int lo_in_seg1 = P.lo[z];
    int n = blockIdx.x;          // 4096 pixels
    int c = threadIdx.x;         // 128 channels
    int ny = n >> 6, nx = n & 63;
    float v = src[((size_t)c * HH + 2 * ny) * WW + 2 * nx];
    unsigned short hi = f2bf(v);
    unsigned short lo = f2bf(v - bf2f(hi));
    unsigned short* drow = dst + (size_t)n * K0S;
    drow[c]       = hi;
    drow[128 + c] = lo_in_seg1 ? lo : hi;
    drow[256 + c] = lo_in_seg1 ? hi : lo;

    float* ssq = P.ssq[z];
    if (ssq) {                   // b images only: per-pixel channel sum of squares
        float s2 = v * v;
#pragma unroll
        for (int o = 32; o; o >>= 1) s2 += __shfl_xor(s2, o);
        if ((threadIdx.x & 63) == 0) partial[threadIdx.x >> 6] = s2;
        __syncthreads();
        if (threadIdx.x == 0) ssq[n] = partial[0] + partial[1];
    }
}

// ---------------- raw 4x4 stride-2 patches of full-res b, transposed: dst[m2][p] bf16 ----------------
__global__ __launch_bounds__(256) void im2col_rawt_kernel(PtrR2 P) {
    int z = blockIdx.z;
    const float* __restrict__ src = P.src[z];
    unsigned short* __restrict__ dst = P.dst[z];
    int idx = blockIdx.x * 256 + threadIdx.x;   // K2*LTOT threads, p fastest
    int p = idx & (LTOT - 1);
    int m = idx >> 12;
    int px = p & 63, py = p >> 6;
    int ke = m & 3, kd = (m >> 2) & 3, c = m >> 4;
    int yy = 2 * py - 1 + kd, xx = 2 * px - 1 + ke;
    float v = 0.f;
    if (yy >= 0 && yy < HH && xx >= 0 && xx < WW)
        v = src[((size_t)c * HH + yy) * WW + xx];
    dst[idx] = f2bf(v);
}

// ---------------- patch inverse norm + mask gate ----------------
__global__ void norm_mm_kernel(PtrN2 P, const float* __restrict__ mask) {
    int z = blockIdx.z;
    const float* __restrict__ ssq = P.ssq[z];
    float* __restrict__ inv_norm = P.invn[z];
    float* __restrict__ mmv = P.mmv[z];
    int p = blockIdx.x * blockDim.x + threadIdx.x;     // 4096
    int px = p & 63, py = p >> 6;
    float s = 0.f, ms = 0.f;
    for (int di = -1; di <= 1; ++di)
        for (int dj = -1; dj <= 1; ++dj) {
            int y = py + di, x = px + dj;
            if (y >= 0 && y < DH && x >= 0 && x < DW) {
                s += ssq[y * 64 + x];
                ms += mask[(size_t)(2 * y) * WW + 2 * x];
            }
        }
    float n = sqrtf(s);
    if (n < 1e-4f) n = 1e-4f;
    inv_norm[p] = 1.f / n;
    mmv[p] = (ms == 0.f) ? 1.f : 0.f;
}

// ---------------- bf16 MFMA GEMM, BK=64, hoisted running pointers, XOR swizzle ----------------
// (kept for GEMM1: M=N=4096, K=384 — short-K, 1024 blocks; not the bottleneck)
__global__ __launch_bounds__(256) void gemm_mfma(
    const unsigned short* __restrict__ Aop, const unsigned short* __restrict__ Bop,
    float* __restrict__ C, int M, int N, int K)
{
    __shared__ short As[128 * 64];
    __shared__ short Bs[128 * 64];
    int tid = threadIdx.x;
    int wave = tid >> 6, lane = tid & 63;
    int wm = (wave >> 1) * 64;
    int wn = (wave & 1) * 64;
    int bm = blockIdx.y * 128, bn = blockIdx.x * 128;

    int rowS = wave * 32;              // wave stages rows [rowS, rowS+32)
    int lrow8 = lane >> 3;             // 0..7 (row within 8-row staging group)
    int gchunk = ((lane & 7) ^ lrow8) * 8;   // swizzled global k-offset (shorts)

    f32x4 acc[4][4] = {};

    int quad = lane >> 4;              // 0..3
    int r16 = lane & 15;
    int pc0 = ((quad)     ^ (r16 & 7)) * 8;  // physical chunk of k-slab 0
    int pc1 = ((4 + quad) ^ (r16 & 7)) * 8;  // physical chunk of k-slab 1

    const unsigned short* ap0 = Aop + (size_t)(bm + rowS +  0 + lrow8) * K + gchunk;
    const unsigned short* ap1 = Aop + (size_t)(bm + rowS +  8 + lrow8) * K + gchunk;
    const unsigned short* ap2 = Aop + (size_t)(bm + rowS + 16 + lrow8) * K + gchunk;
    const unsigned short* ap3 = Aop + (size_t)(bm + rowS + 24 + lrow8) * K + gchunk;
    const unsigned short* bp0 = Bop + (size_t)(bn + rowS +  0 + lrow8) * K + gchunk;
    const unsigned short* bp1 = Bop + (size_t)(bn + rowS +  8 + lrow8) * K + gchunk;
    const unsigned short* bp2 = Bop + (size_t)(bn + rowS + 16 + lrow8) * K + gchunk;
    const unsigned short* bp3 = Bop + (size_t)(bn + rowS + 24 + lrow8) * K + gchunk;
    short* lA = As + rowS * 64;        // wave-uniform LDS bases
    short* lB = Bs + rowS * 64;

    for (int k0 = 0; k0 < K; k0 += 64) {
        GLDS16(ap0, lA);            GLDS16(ap1, lA + 8 * 64);
        GLDS16(ap2, lA + 16 * 64);  GLDS16(ap3, lA + 24 * 64);
        GLDS16(bp0, lB);            GLDS16(bp1, lB + 8 * 64);
        GLDS16(bp2, lB + 16 * 64);  GLDS16(bp3, lB + 24 * 64);
        ap0 += 64; ap1 += 64; ap2 += 64; ap3 += 64;
        bp0 += 64; bp1 += 64; bp2 += 64; bp3 += 64;
        __syncthreads();

        short8 a0[4], b0[4], a1[4], b1[4];
#pragma unroll
        for (int i = 0; i < 4; ++i) {
            a0[i] = *(const short8*)&As[(wm + i * 16 + r16) * 64 + pc0];
            b0[i] = *(const short8*)&Bs[(wn + i * 16 + r16) * 64 + pc0];
            a1[i] = *(const short8*)&As[(wm + i * 16 + r16) * 64 + pc1];
            b1[i] = *(const short8*)&Bs[(wn + i * 16 + r16) * 64 + pc1];
        }
#pragma unroll
        for (int i = 0; i < 4; ++i)
#pragma unroll
            for (int j = 0; j < 4; ++j) {
                acc[i][j] = __builtin_amdgcn_mfma_f32_16x16x32_bf16(a0[i], b0[j], acc[i][j], 0, 0, 0);
                acc[i][j] = __builtin_amdgcn_mfma_f32_16x16x32_bf16(a1[i], b1[j], acc[i][j], 0, 0, 0);
            }
        __syncthreads();
    }

    int col = lane & 15, rq = (lane >> 4) * 4;
#pragma unroll
    for (int i = 0; i < 4; ++i) {
#pragma unroll
        for (int r = 0; r < 4; ++r) {
            int m = bm + wm + i * 16 + rq + r;
#pragma unroll
            for (int j = 0; j < 4; ++j)
                C[(size_t)m * N + bn + wn + j * 16 + col] = acc[i][j][r];
        }
    }
}

// ---------------- GEMM2: 256x256, split-K/2, m201-style 8-phase half-tile pipeline ----------------
// R6: R5's one-barrier loop kept all 8 waves phase-locked: ds_read (2304 cyc) and MFMA (2484)
// per K-tile fully serialized (observed 4912, MfmaUtil 41%). Port of the verified 8-phase
// template (1563 TF @4k): per K-tile 4 phases, each {ds_read subtile | stage half-tile | BAR |
// lgkmcnt(0)+sched_barrier | setprio(1) 16 MFMA setprio(0) | BAR}. Balanced reads 8/4/8/4 via
// cross-tile b01 prefetch in ph4. LDS = 2 dbuf x 2 half x (128x64) x {A,B} = 128 KB; half-tile
// recycling: stage B(t+2) at ph3 (B(t) reads done by ph2's lgkm0+BAR), A(t+2) at ph4.
// vmcnt(4) once per K-tile at ph4 head (retires tile t+1 fully BEFORE the b01(t+1) ds_read;
// leaves ph3's 4 B-stage loads in flight); vmcnt(0) only for the last two tiles.
__global__ __launch_bounds__(512, 2) void gemm_k2(
    const unsigned short* __restrict__ Aop, const unsigned short* __restrict__ Bop,
    float* __restrict__ Cpart)
{
    constexpr int NT = 32;                    // GKH / 64
    __shared__ short lds[65536];              // 128 KB: A[d][h][8192] | B at +32768
    int tid = threadIdx.x;
    int wave = tid >> 6, lane = tid & 63;
    int wm = (wave >> 2) * 128;               // 0,128
    int wn = (wave & 3) * 64;                 // 0,64,128,192
    int bm = blockIdx.y * 256, bn = blockIdx.x * 256;
    int ks = blockIdx.z;                      // K half
    int lrow8 = lane >> 3;
    int gchunk = ((lane & 7) ^ lrow8) * 8;    // pre-swizzled global k-offset (shorts)
    int r16 = lane & 15, quad = lane >> 4;
    int pc0 = ((quad)     ^ (r16 & 7)) * 8;
    int pc1 = ((4 + quad) ^ (r16 & 7)) * 8;
    int ha = wave >> 2;                       // wave's A-half
    int hb = (wave & 3) >> 1;                 // wave's B-half

    // staging pointers: (h,g) -> rows h*128 + wave*16 + g*8 (+lrow8); uniform 2 glds/wave/half
    const size_t ko = (size_t)ks * GKH + gchunk;
    const unsigned short* aS00 = Aop + (size_t)(bm +       wave * 16 +     lrow8) * GK + ko;
    const unsigned short* aS01 = Aop + (size_t)(bm +       wave * 16 + 8 + lrow8) * GK + ko;
    const unsigned short* aS10 = Aop + (size_t)(bm + 128 + wave * 16 +     lrow8) * GK + ko;
    const unsigned short* aS11 = Aop + (size_t)(bm + 128 + wave * 16 + 8 + lrow8) * GK + ko;
    const unsigned short* bS00 = Bop + (size_t)(bn +       wave * 16 +     lrow8) * GK + ko;
    const unsigned short* bS01 = Bop + (size_t)(bn +       wave * 16 + 8 + lrow8) * GK + ko;
    const unsigned short* bS10 = Bop + (size_t)(bn + 128 + wave * 16 +     lrow8) * GK + ko;
    const unsigned short* bS11 = Bop + (size_t)(bn + 128 + wave * 16 + 8 + lrow8) * GK + ko;

    const short* ArdH = lds + ha * 8192;                              // + d*16384
    const short* BrdH = lds + 32768 + hb * 8192 + (wn & 64) * 64;     // + d*16384
    short* AstH = lds + (wave * 16) * 64;                             // + d*16384 + h*8192
    short* BstH = lds + 32768 + (wave * 16) * 64;

    f32x4 acc[8][4] = {};
    short8 aa0[4], aa1[4], b0[4], b1[4];

#define STAGE_B2(d) do { short* p = BstH + (d) * 16384; \
    GLDS16(bS00, p);        GLDS16(bS01, p + 512); \
    GLDS16(bS10, p + 8192); GLDS16(bS11, p + 8192 + 512); \
    bS00 += 64; bS01 += 64; bS10 += 64; bS11 += 64; } while (0)
#define STAGE_A2(d) do { short* p = AstH + (d) * 16384; \
    GLDS16(aS00, p);        GLDS16(aS01, p + 512); \
    GLDS16(aS10, p + 8192); GLDS16(aS11, p + 8192 + 512); \
    aS00 += 64; aS01 += 64; aS10 += 64; aS11 += 64; } while (0)
#define BARRIER do { __builtin_amdgcn_s_barrier(); asm volatile("" ::: "memory"); } while (0)
#define WAIT_LGKM0 do { asm volatile("s_waitcnt lgkmcnt(0)" ::: "memory"); \
    __builtin_amdgcn_sched_barrier(0); } while (0)
#define MFMA_BF16 __builtin_amdgcn_mfma_f32_16x16x32_bf16

    // prologue: stage tiles 0,1; tile 0 resident (tile 1's 8 loads stay in flight)
    STAGE_B2(0); STAGE_A2(0); STAGE_B2(1); STAGE_A2(1);
    asm volatile("s_waitcnt vmcnt(8)" ::: "memory");
    BARRIER;
    {   // prefetch b01 of tile 0 (waited at ph1's lgkm0)
        const short* Bb = BrdH;
        b0[0] = *(const short8*)&Bb[(r16) * 64 + pc0];
        b1[0] = *(const short8*)&Bb[(r16) * 64 + pc1];
        b0[1] = *(const short8*)&Bb[(16 + r16) * 64 + pc0];
        b1[1] = *(const short8*)&Bb[(16 + r16) * 64 + pc1];
    }

#pragma unroll 1
    for (int t = 0; t < NT; ++t) {
        int d = t & 1;
        const short* Ab = ArdH + d * 16384;
        const short* Bb = BrdH + d * 16384;

        // ---- ph1: read a-low (8); MFMA (0..3)x(0,1)
#pragma unroll
        for (int ii = 0; ii < 4; ++ii) {
            aa0[ii] = *(const short8*)&Ab[(ii * 16 + r16) * 64 + pc0];
            aa1[ii] = *(const short8*)&Ab[(ii * 16 + r16) * 64 + pc1];
        }
        BARRIER; WAIT_LGKM0;
        __builtin_amdgcn_s_setprio(1);
#pragma unroll
        for (int ii = 0; ii < 4; ++ii)
#pragma unroll
            for (int j = 0; j < 2; ++j) {
                acc[ii][j] = MFMA_BF16(aa0[ii], b0[j], acc[ii][j], 0, 0, 0);
                acc[ii][j] = MFMA_BF16(aa1[ii], b1[j], acc[ii][j], 0, 0, 0);
            }
        __builtin_amdgcn_s_setprio(0);
        BARRIER;

        // ---- ph2: read b23 (4); MFMA (0..3)x(2,3)
        b0[2] = *(const short8*)&Bb[(32 + r16) * 64 + pc0];
        b1[2] = *(const short8*)&Bb[(32 + r16) * 64 + pc1];
        b0[3] = *(const short8*)&Bb[(48 + r16) * 64 + pc0];
        b1[3] = *(const short8*)&Bb[(48 + r16) * 64 + pc1];
        BARRIER; WAIT_LGKM0;
        __builtin_amdgcn_s_setprio(1);
#pragma unroll
        for (int ii = 0; ii < 4; ++ii)
#pragma unroll
            for (int j = 2; j < 4; ++j) {
                acc[ii][j] = MFMA_BF16(aa0[ii], b0[j], acc[ii][j], 0, 0, 0);
                acc[ii][j] = MFMA_BF16(aa1[ii], b1[j], acc[ii][j], 0, 0, 0);
            }
        __builtin_amdgcn_s_setprio(0);
        BARRIER;

        // ---- ph3: read a-high (8); stage B(t+2) into slot d (B(t) reads done); MFMA (4..7)x(0,1)
#pragma unroll
        for (int ii = 0; ii < 4; ++ii) {
            aa0[ii] = *(const short8*)&Ab[(64 + ii * 16 + r16) * 64 + pc0];
            aa1[ii] = *(const short8*)&Ab[(64 + ii * 16 + r16) * 64 + pc1];
        }
        if (t + 2 < NT) STAGE_B2(d);
        BARRIER; WAIT_LGKM0;
        __builtin_amdgcn_s_setprio(1);
#pragma unroll
        for (int ii = 0; ii < 4; ++ii)
#pragma unroll
            for (int j = 0; j < 2; ++j) {
                acc[4 + ii][j] = MFMA_BF16(aa0[ii], b0[j], acc[4 + ii][j], 0, 0, 0);
                acc[4 + ii][j] = MFMA_BF16(aa1[ii], b1[j], acc[4 + ii][j], 0, 0, 0);
            }
        __builtin_amdgcn_s_setprio(0);
        BARRIER;

        // ---- ph4: vmcnt gate; prefetch b01(t+1); stage A(t+2); MFMA (4..7)x(2,3)
        // vmcnt(4): retires A(t+1)+B(t+1) (so b01(t+1) read + next ph1 are safe),
        // leaves ph3's 4 B(t+2)-stage loads in flight. Tail: drain fully.
        if (t + 2 < NT) { asm volatile("s_waitcnt vmcnt(4)" ::: "memory"); }
        else            { asm volatile("s_waitcnt vmcnt(0)" ::: "memory"); }
        if (t + 1 < NT) {
            const short* Bn = BrdH + (d ^ 1) * 16384;
            b0[0] = *(const short8*)&Bn[(r16) * 64 + pc0];
            b1[0] = *(const short8*)&Bn[(r16) * 64 + pc1];
            b0[1] = *(const short8*)&Bn[(16 + r16) * 64 + pc0];
            b1[1] = *(const short8*)&Bn[(16 + r16) * 64 + pc1];
        }
        if (t + 2 < NT) STAGE_A2(d);
        BARRIER; WAIT_LGKM0;
        __builtin_amdgcn_s_setprio(1);
#pragma unroll
        for (int ii = 0; ii < 4; ++ii)
#pragma unroll
            for (int j = 2; j < 4; ++j) {
                acc[4 + ii][j] = MFMA_BF16(aa0[ii], b0[j], acc[4 + ii][j], 0, 0, 0);
                acc[4 + ii][j] = MFMA_BF16(aa1[ii], b1[j], acc[4 + ii][j], 0, 0, 0);
            }
        __builtin_amdgcn_s_setprio(0);
        BARRIER;
    }
#undef STAGE_B2
#undef STAGE_A2
#undef BARRIER
#undef WAIT_LGKM0
#undef MFMA_BF16

    float* Cout = Cpart + (size_t)ks * K2 * LTOT;
    int col = lane & 15, rq = (lane >> 4) * 4;
#pragma unroll
    for (int i = 0; i < 8; ++i) {
#pragma unroll
        for (int r = 0; r < 4; ++r) {
            int m = bm + wm + i * 16 + rq + r;
#pragma unroll
            for (int j = 0; j < 4; ++j)
                Cout[(size_t)m * LTOT + bn + wn + j * 16 + col] = acc[i][j][r];
        }
    }
}

// ---------------- 9-tap patch stencil, VECTORIZED: thread t owns 16 consecutive cols p0=16t ----------------
__global__ __launch_bounds__(256) void stencil_norm_kernel(
    const float* __restrict__ C, const float* __restrict__ invn,
    float* __restrict__ Sg)
{
    int blk = blockIdx.x;
    int q = ((blk & 7) << 9) | (blk >> 3);   // XCD swizzle: contiguous 512-q per XCD
    int t = threadIdx.x;
    int qy = q >> 6, qx = q & 63;
    int chunk = t >> 2;                      // py (uniform over the 16 cols)
    int lanebase = (t & 3) << 4;             // px of first col
    int p0 = t << 4;

    f32x4 acc[4];
#pragma unroll
    for (int g = 0; g < 4; ++g) { acc[g][0] = acc[g][1] = acc[g][2] = acc[g][3] = 0.f; }

#pragma unroll
    for (int du = -1; du <= 1; ++du) {
        if (qy + du < 0 || qy + du > 63) continue;
        if (chunk + du < 0 || chunk + du > 63) continue;   // py+du (uniform)
#pragma unroll
        for (int dv = -1; dv <= 1; ++dv) {
            if (qx + dv < 0 || qx + dv > 63) continue;
            const float* rowp = C + (size_t)(q + 64 * du + dv) * LTOT + 64 * du + dv + p0;
#pragma unroll
            for (int g = 0; g < 4; ++g) {
                f32x4 lv = ld4u(rowp + 4 * g);
                if (dv == -1 && g == 0 && lanebase == 0)  lv[0] = 0.f;  // px+dv = -1
                if (dv ==  1 && g == 3 && lanebase == 48) lv[3] = 0.f;  // px+dv = 64
                acc[g] += lv;
            }
        }
    }
    float* orow = Sg + (size_t)q * PSTR;
#pragma unroll
    for (int g = 0; g < 4; ++g) {
        f32x4 iv = *(const f32x4*)(invn + p0 + 4 * g);
        *(f32x4*)(orow + p0 + 4 * g) = acc[g] * iv;
    }
    // zero this row's column pads (reads touch cols -1 .. 4099)
    if (t == 0) { orow[-4] = orow[-3] = orow[-2] = orow[-1] = 0.f; }
    else if (t == 1) { orow[4096] = orow[4097] = orow[4098] = orow[4099] = 0.f; }
    // zero guard rows -1 and 4096 (full padded rows)
    if (q == 0) {
        float* gr = Sg - 4 - PSTR;
        for (int k = t; k < PSTR; k += 256) gr[k] = 0.f;
    }
    if (q == 4095) {
        float* gr = Sg - 4 + (size_t)4096 * PSTR;
        for (int k = t; k < PSTR; k += 256) gr[k] = 0.f;
    }
}

// ---------------- fused (fuse2 o fuse1) stencil + row softmax + bf16, VECTORIZED ----------------
__global__ __launch_bounds__(256) void fused_conv_softmax_kernel(
    const float* __restrict__ Sg, const float* __restrict__ mmv,
    unsigned short* __restrict__ S16)
{
    __shared__ float redmax[4];
    __shared__ float redsum[4];
    int blk = blockIdx.x;
    int q = ((blk & 7) << 9) | (blk >> 3);
    int t = threadIdx.x;
    int lane = t & 63, wid = t >> 6;
    int chunk = t >> 2;
    int lanebase = (t & 3) << 4;
    int c0 = t << 4;

    int rbase = ((q & 63) << 6) | (q >> 6);     // swap(q)

    f32x4 sacc[4];
#pragma unroll
    for (int g = 0; g < 4; ++g) { sacc[g][0] = sacc[g][1] = sacc[g][2] = sacc[g][3] = 0.f; }

#pragma unroll
    for (int j = 0; j < 3; ++j) {               // d2 = j-1 (fuse2, flat bounds in swapped space)
        int r2 = rbase + (j - 1);
        if (r2 < 0 || r2 >= LTOT) continue;     // block-uniform
        int rr = ((r2 & 63) << 6) | (r2 >> 6);  // swap(r2)
        int cj = chunk + (j - 1);
        int ccb;
        if (cj < 0)       ccb = 4031 + lanebase;
        else if (cj > 63) ccb = lanebase + 1;
        else              ccb = (cj << 6) + lanebase;
        const float* pr = Sg + (size_t)rr * PSTR + ccb;
#pragma unroll
        for (int g = 0; g < 4; ++g) {
            const float* pg = pr + 4 * g;
            f32x4 lm = ld4u(pg - (PSTR + 1));   // d1 = -1: row rr-1, col cc-1
            f32x4 l0 = ld4u(pg);                // d1 =  0
            f32x4 lp = ld4u(pg + (PSTR + 1));   // d1 = +1
            f32x4 tj = lm + l0 + lp;
            if (j == 0 && g == 0 && t == 0)   tj[0] = 0.f;   // c=0 corner (c2=-1)
            if (j == 2 && g == 3 && t == 255) tj[3] = 0.f;   // c=4095 corner (c2=4096)
            sacc[g] += tj;
        }
    }

    float v[16];
#pragma unroll
    for (int g = 0; g < 4; ++g) {
        f32x4 m4 = *(const f32x4*)(mmv + c0 + 4 * g);
#pragma unroll
        for (int e = 0; e < 4; ++e)
            v[4 * g + e] = sacc[g][e] * m4[e] * SCALE_F;
    }
#pragma unroll
    for (int k = 0; k < 16; ++k) asm volatile("" : "+v"(v[k]));   // pin: no remat of the stencil

    float mx = v[0];
#pragma unroll
    for (int i = 1; i < 16; ++i) mx = fmaxf(mx, v[i]);
#pragma unroll
    for (int o = 32; o; o >>= 1) mx = fmaxf(mx, __shfl_xor(mx, o));
    if (lane == 0) redmax[wid] = mx;
    __syncthreads();
    float gmx = fmaxf(fmaxf(redmax[0], redmax[1]), fmaxf(redmax[2], redmax[3]));

    float s = 0.f;
#pragma unroll
    for (int i = 0; i < 16; ++i) {
        v[i] = __expf(v[i] - gmx);
        s += v[i];
    }
#pragma unroll
    for (int o = 32; o; o >>= 1) s += __shfl_xor(s, o);
    if (lane == 0) redsum[wid] = s;
    __syncthreads();
    float inv = 1.f / (redsum[0] + redsum[1] + redsum[2] + redsum[3]);

    unsigned short* orow = S16 + (size_t)q * LTOT + c0;
    short8 h0, h1;
#pragma unroll
    for (int e = 0; e < 8; ++e) {
        h0[e] = (short)f2bf(v[e]     * inv * mmv[c0 + e]);
        h1[e] = (short)f2bf(v[8 + e] * inv * mmv[c0 + 8 + e]);
    }
    *(short8*)orow = h0;
    *(short8*)(orow + 8) = h1;
}

// ---------------- overlap-add of weighted 4x4 patches (stride 2), /4 ----------------
// C2t is TRANSPOSED and SPLIT-K: two partials [m2][q]; taps contiguous across threads (x->ox).
__global__ void output_kernel(const float* __restrict__ C2t, float* __restrict__ out) {
    const float* __restrict__ P1 = C2t + (size_t)K2 * LTOT;
    int idx = blockIdx.x * blockDim.x + threadIdx.x;   // CC*HH*WW
    int x = idx & 127;
    int y = (idx >> 7) & 127;
    int c = idx >> 14;
    int oylo = max(0, (y - 1) >> 1), oyhi = min(63, (y + 1) >> 1);
    int oxlo = max(0, (x - 1) >> 1), oxhi = min(63, (x + 1) >> 1);
    float s = 0.f;
    for (int oy = oylo; oy <= oyhi; ++oy)
        for (int ox = oxlo; ox <= oxhi; ++ox) {
            int kd = y - 2 * oy + 1;
            int ke = x - 2 * ox + 1;
            size_t off = (size_t)(c * 16 + kd * 4 + ke) * LTOT + oy * 64 + ox;
            s += C2t[off] + P1[off];
        }
    out[idx] = s * 0.25f;
}

extern "C" void kernel_launch(void* const* d_in, const int* in_sizes, int n_in,
                              void* d_out, int out_size, void* d_ws, size_t ws_size,
                              hipStream_t stream) {
    (void)in_sizes; (void)n_in; (void)out_size; (void)ws_size;
    const float* f    = (const float*)d_in[0];
    const float* b    = (const float*)d_in[1];
    const float* mask = (const float*)d_in[2];
    float* out = (float*)d_out;

    const size_t SZ_MAT  = (size_t)LTOT * LTOT * 4;        // 64 MB
    const size_t SZ_SPAD = (size_t)PSTR * 4098 * 4;        // 67.3 MB padded S (guards + col pads)
    const size_t SZ_WR   = (size_t)K2 * LTOT * 2;          // 16 MB
    const size_t SZ_SP   = (size_t)LTOT * K0S * 2;         // 3 MB
    const size_t SZ_V    = (size_t)LTOT * 4;

    auto pad = [](size_t n) { return (n + 255) & ~(size_t)255; };
    char* p = (char*)d_ws;
    auto take = [&](size_t n) -> void* { void* r = (void*)p; p += pad(n); return r; };

    // footprint: 0.25K guard + 64 + 67.3 + 16 (single W) + 4*3 + small ~= 160 MB (< proven 172)
    take(256);                                     // guard: stencil corner reads C[-1]
    float* Buf1 = (float*)take(SZ_MAT);            // Cpix -> S16 (lower 32 MB)
    float* Spad = (float*)take(SZ_SPAD);           // padded S -> C2t partials (lower 64 MB)
    unsigned short* W = (unsigned short*)take(SZ_WR);   // per-batch raw patches (im2col in loop)
    unsigned short* Bsp0 = (unsigned short*)take(SZ_SP);
    unsigned short* Fsp0 = (unsigned short*)take(SZ_SP);
    unsigned short* Bsp1 = (unsigned short*)take(SZ_SP);
    unsigned short* Fsp1 = (unsigned short*)take(SZ_SP);
    float* ssq0 = (float*)take(SZ_V);  float* ssq1 = (float*)take(SZ_V);
    float* invn0 = (float*)take(SZ_V); float* invn1 = (float*)take(SZ_V);
    float* mmv0 = (float*)take(SZ_V);  float* mmv1 = (float*)take(SZ_V);

    const float* f0 = f,  *b0 = b;
    const float* f1 = f + IMG, *b1 = b + IMG;

    float* Sg = Spad + PSTR + 4;                   // padded S row 0, col 0
    unsigned short* S16 = (unsigned short*)Buf1;   // 32 MB, after Cpix dead
    float* C2t = Spad;                             // 2 x 32 MB partials, after padded S dead

    // ---- merged prep (both batches); ssq fused into the b split passes ----
    Prep4 P{{b0, f0, b1, f1}, {Bsp0, Fsp0, Bsp1, Fsp1},
            {ssq0, nullptr, ssq1, nullptr}, {1, 0, 1, 0}};
    split_ds_kernel<<<dim3(LTOT, 1, 4), 128, 0, stream>>>(P);
    PtrN2 nm{{ssq0, ssq1}, {invn0, invn1}, {mmv0, mmv1}};
    norm_mm_kernel<<<dim3(16, 1, 2), 256, 0, stream>>>(nm, mask);

    // ---- per-batch pipeline ----
    for (int bi = 0; bi < 2; ++bi) {
        const unsigned short* Fsp = bi ? Fsp1 : Fsp0;
        const unsigned short* Bsp = bi ? Bsp1 : Bsp0;
        const float* invn = bi ? invn1 : invn0;
        const float* mmv  = bi ? mmv1 : mmv0;

        // raw 4x4 patches for this batch only (W reused across batches)
        PtrR2 rw{{bi ? b1 : b0, nullptr}, {W, nullptr}};
        im2col_rawt_kernel<<<dim3((size_t)K2 * LTOT / 256, 1, 1), 256, 0, stream>>>(rw);

        // Cpix[q][p] = sum_c fd[c][q]*bd[c][p]   (split-concat fp32-accurate, K=384)
        gemm_mfma<<<dim3(32, 32), 256, 0, stream>>>(Fsp, Bsp, Buf1, LTOT, LTOT, K0S);

        // patch inner products: 9-tap diagonal stencil + invn column scale -> padded S
        stencil_norm_kernel<<<LTOT, 256, 0, stream>>>(Buf1, invn, Sg);

        // fused (fuse2 o fuse1) + softmax + bf16 cast  (Cpix dead -> S16 in Buf1 lower half)
        fused_conv_softmax_kernel<<<LTOT, 256, 0, stream>>>(Sg, mmv, S16);

        // TRANSPOSED GEMM2, 256^2-tile split-K/2, 8-phase: C2t_ks[m2][q] = sum_p W[m2][p]*S16[q][p]
        gemm_k2<<<dim3(LTOT / 256, K2 / 256, 2), 512, 0, stream>>>(W, S16, C2t);

        output_kernel<<<CC * HH * WW / 256, 256, 0, stream>>>(C2t, out + (size_t)bi * IMG);
    }
}

// Round 7
// 517.209 us; speedup vs baseline: 1.0145x; 1.0145x over previous
//
#include <hip/hip_runtime.h>

#define CC 128
#define HH 128
#define WW 128
#define DH 64
#define DW 64
#define LTOT 4096          // DH*DW patches / fg positions
#define K0S 384            // 3*128 split-concat K for the pixel-pair GEMM
#define K2 2048            // CC*4*4
#define GK 4096            // GEMM2 full K
#define GKH 2048           // GEMM2 half K (split-K by 2)
#define SCALE_F 10.0f
#define IMG ((size_t)CC * HH * WW)
#define PSTR 4104          // padded S row stride (floats): 4 pad | 4096 | 4 pad; %4==0 keeps 16B align

typedef __attribute__((ext_vector_type(8))) short short8;
typedef __attribute__((ext_vector_type(4))) float f32x4;

// ---- pointer-pack structs (batch-merged prep via blockIdx.z) ----
struct Prep4 { const float* src[4]; unsigned short* dst[4]; float* ssq[4]; int lo[4]; };
struct PtrN2 { const float* ssq[2]; float* invn[2]; float* mmv[2]; };
struct PtrR2 { const float* src[2]; unsigned short* dst[2]; };

// ---- bf16 helpers (RNE) ----
__device__ __forceinline__ unsigned short f2bf(float x) {
    union { float f; unsigned u; } v; v.f = x;
    unsigned r = v.u + 0x7fffu + ((v.u >> 16) & 1u);
    return (unsigned short)(r >> 16);
}
__device__ __forceinline__ float bf2f(unsigned short b) {
    union { unsigned u; float f; } v; v.u = ((unsigned)b) << 16;
    return v.f;
}

// unaligned (4B-aligned) float4 load
__device__ __forceinline__ f32x4 ld4u(const float* p) {
    f32x4 r; __builtin_memcpy(&r, p, 16); return r;
}

#define GLDS16(g, l) __builtin_amdgcn_global_load_lds( \
    (const __attribute__((address_space(1))) void*)(g), \
    (__attribute__((address_space(3))) void*)(l), 16, 0, 0)

// ---------------- downsample (::2) + fp32->bf16 split + (for b) fused ssq reduce ----------------
// b gets [hi, lo, hi], f gets [hi, hi, lo]  =>  products sum to hi*hi + lo*hi + hi*lo
__global__ __launch_bounds__(128) void split_ds_kernel(Prep4 P) {
    __shared__ float partial[2];
    int z = blockIdx.z;
    const float* __restrict__ src = P.src[z];
    unsigned short* __restrict__ dst = P.dst[z];
    int lo_in_seg1 = P.lo[z];
    int n = blockIdx.x;          // 4096 pixels
    int c = threadIdx.x;         // 128 channels
    int ny = n >> 6, nx = n & 63;
    float v = src[((size_t)c * HH + 2 * ny) * WW + 2 * nx];
    unsigned short hi = f2bf(v);
    unsigned short lo = f2bf(v - bf2f(hi));
    unsigned short* drow = dst + (size_t)n * K0S;
    drow[c]       = hi;
    drow[128 + c] = lo_in_seg1 ? lo : hi;
    drow[256 + c] = lo_in_seg1 ? hi : lo;

    float* ssq = P.ssq[z];
    if (ssq) {                   // b images only: per-pixel channel sum of squares
        float s2 = v * v;
#pragma unroll
        for (int o = 32; o; o >>= 1) s2 += __shfl_xor(s2, o);
        if ((threadIdx.x & 63) == 0) partial[threadIdx.x >> 6] = s2;
        __syncthreads();
        if (threadIdx.x == 0) ssq[n] = partial[0] + partial[1];
    }
}

// ---------------- raw 4x4 stride-2 patches of full-res b, transposed: dst[m2][p] bf16 ----------------
__global__ __launch_bounds__(256) void im2col_rawt_kernel(PtrR2 P) {
    int z = blockIdx.z;
    const float* __restrict__ src = P.src[z];
    unsigned short* __restrict__ dst = P.dst[z];
    int idx = blockIdx.x * 256 + threadIdx.x;   // K2*LTOT threads, p fastest
    int p = idx & (LTOT - 1);
    int m = idx >> 12;
    int px = p & 63, py = p >> 6;
    int ke = m & 3, kd = (m >> 2) & 3, c = m >> 4;
    int yy = 2 * py - 1 + kd, xx = 2 * px - 1 + ke;
    float v = 0.f;
    if (yy >= 0 && yy < HH && xx >= 0 && xx < WW)
        v = src[((size_t)c * HH + yy) * WW + xx];
    dst[idx] = f2bf(v);
}

// ---------------- patch inverse norm + mask gate ----------------
__global__ void norm_mm_kernel(PtrN2 P, const float* __restrict__ mask) {
    int z = blockIdx.z;
    const float* __restrict__ ssq = P.ssq[z];
    float* __restrict__ inv_norm = P.invn[z];
    float* __restrict__ mmv = P.mmv[z];
    int p = blockIdx.x * blockDim.x + threadIdx.x;     // 4096
    int px = p & 63, py = p >> 6;
    float s = 0.f, ms = 0.f;
    for (int di = -1; di <= 1; ++di)
        for (int dj = -1; dj <= 1; ++dj) {
            int y = py + di, x = px + dj;
            if (y >= 0 && y < DH && x >= 0 && x < DW) {
                s += ssq[y * 64 + x];
                ms += mask[(size_t)(2 * y) * WW + 2 * x];
            }
        }
    float n = sqrtf(s);
    if (n < 1e-4f) n = 1e-4f;
    inv_norm[p] = 1.f / n;
    mmv[p] = (ms == 0.f) ? 1.f : 0.f;
}

// ---------------- bf16 MFMA GEMM, BK=64, hoisted running pointers, XOR swizzle ----------------
// (kept for GEMM1: M=N=4096, K=384 — short-K, 1024 blocks; write-bound, 4 blocks/CU overlap)
__global__ __launch_bounds__(256) void gemm_mfma(
    const unsigned short* __restrict__ Aop, const unsigned short* __restrict__ Bop,
    float* __restrict__ C, int M, int N, int K)
{
    __shared__ short As[128 * 64];
    __shared__ short Bs[128 * 64];
    int tid = threadIdx.x;
    int wave = tid >> 6, lane = tid & 63;
    int wm = (wave >> 1) * 64;
    int wn = (wave & 1) * 64;
    int bm = blockIdx.y * 128, bn = blockIdx.x * 128;

    int rowS = wave * 32;              // wave stages rows [rowS, rowS+32)
    int lrow8 = lane >> 3;             // 0..7 (row within 8-row staging group)
    int gchunk = ((lane & 7) ^ lrow8) * 8;   // swizzled global k-offset (shorts)

    f32x4 acc[4][4] = {};

    int quad = lane >> 4;              // 0..3
    int r16 = lane & 15;
    int pc0 = ((quad)     ^ (r16 & 7)) * 8;  // physical chunk of k-slab 0
    int pc1 = ((4 + quad) ^ (r16 & 7)) * 8;  // physical chunk of k-slab 1

    const unsigned short* ap0 = Aop + (size_t)(bm + rowS +  0 + lrow8) * K + gchunk;
    const unsigned short* ap1 = Aop + (size_t)(bm + rowS +  8 + lrow8) * K + gchunk;
    const unsigned short* ap2 = Aop + (size_t)(bm + rowS + 16 + lrow8) * K + gchunk;
    const unsigned short* ap3 = Aop + (size_t)(bm + rowS + 24 + lrow8) * K + gchunk;
    const unsigned short* bp0 = Bop + (size_t)(bn + rowS +  0 + lrow8) * K + gchunk;
    const unsigned short* bp1 = Bop + (size_t)(bn + rowS +  8 + lrow8) * K + gchunk;
    const unsigned short* bp2 = Bop + (size_t)(bn + rowS + 16 + lrow8) * K + gchunk;
    const unsigned short* bp3 = Bop + (size_t)(bn + rowS + 24 + lrow8) * K + gchunk;
    short* lA = As + rowS * 64;        // wave-uniform LDS bases
    short* lB = Bs + rowS * 64;

    for (int k0 = 0; k0 < K; k0 += 64) {
        GLDS16(ap0, lA);            GLDS16(ap1, lA + 8 * 64);
        GLDS16(ap2, lA + 16 * 64);  GLDS16(ap3, lA + 24 * 64);
        GLDS16(bp0, lB);            GLDS16(bp1, lB + 8 * 64);
        GLDS16(bp2, lB + 16 * 64);  GLDS16(bp3, lB + 24 * 64);
        ap0 += 64; ap1 += 64; ap2 += 64; ap3 += 64;
        bp0 += 64; bp1 += 64; bp2 += 64; bp3 += 64;
        __syncthreads();

        short8 a0[4], b0[4], a1[4], b1[4];
#pragma unroll
        for (int i = 0; i < 4; ++i) {
            a0[i] = *(const short8*)&As[(wm + i * 16 + r16) * 64 + pc0];
            b0[i] = *(const short8*)&Bs[(wn + i * 16 + r16) * 64 + pc0];
            a1[i] = *(const short8*)&As[(wm + i * 16 + r16) * 64 + pc1];
            b1[i] = *(const short8*)&Bs[(wn + i * 16 + r16) * 64 + pc1];
        }
#pragma unroll
        for (int i = 0; i < 4; ++i)
#pragma unroll
            for (int j = 0; j < 4; ++j) {
                acc[i][j] = __builtin_amdgcn_mfma_f32_16x16x32_bf16(a0[i], b0[j], acc[i][j], 0, 0, 0);
                acc[i][j] = __builtin_amdgcn_mfma_f32_16x16x32_bf16(a1[i], b1[j], acc[i][j], 0, 0, 0);
            }
        __syncthreads();
    }

    int col = lane & 15, rq = (lane >> 4) * 4;
#pragma unroll
    for (int i = 0; i < 4; ++i) {
#pragma unroll
        for (int r = 0; r < 4; ++r) {
            int m = bm + wm + i * 16 + rq + r;
#pragma unroll
            for (int j = 0; j < 4; ++j)
                C[(size_t)m * N + bn + wn + j * 16 + col] = acc[i][j][r];
        }
    }
}

// ---------------- GEMM2: 256x256, split-K/2, ring-2 counted vmcnt (R5 body) + XCD panel swizzle ----------------
// R7: R3/R5/R6 all land 65-72 µs while MfmaUtil wiggles -> schedule is not the binding
// resource. Invariant: 512 MB/dispatch staged through L2/L3 (A-panels x16 bn-readers,
// B-panels x8 bm-readers) = 7.8 TB/s cache-fabric demand ~ the Infinity-Cache ceiling.
// Without XCD grouping, each panel's readers round-robin all 8 XCDs -> every XCD L2
// re-fetches every panel from L3 (~384 MB L3-side). Fix: flat 256-block grid (1/CU,
// 32/XCD), decode so all 8 bm-blocks of one (bn,ks) B-panel share an XCD:
//   xcd=flat&7, slot=(flat>>3)&3, bm=flat>>5, P=slot*8+xcd, bn=P>>1, ks=P&1
// B-panels then hit L3 once (32 MB), A-panels 8x (128 MB) -> ~160 MB L3 traffic; L2
// (34.5 TB/s) carries the re-reads. Compute floor becomes binding. Math identical to R5.
__global__ __launch_bounds__(512, 2) void gemm_k2(
    const unsigned short* __restrict__ Aop, const unsigned short* __restrict__ Bop,
    float* __restrict__ Cpart)
{
    constexpr int NT = 32;                    // GKH / 64
    constexpr int BUFS = 512 * 64;            // shorts per ring slot (64 KB: A 256 rows + B 256 rows)
    __shared__ short lds[2 * BUFS];           // 128 KB
    int flat = blockIdx.x;
    int xcd  = flat & 7;
    int slot = (flat >> 3) & 3;
    int bmId = flat >> 5;                     // 0..7
    int P    = slot * 8 + xcd;                // 0..31
    int bnId = P >> 1;                        // 0..15
    int ks   = P & 1;                         // K half
    int bm = bmId * 256, bn = bnId * 256;

    int tid = threadIdx.x;
    int wave = tid >> 6, lane = tid & 63;
    int wm = (wave >> 2) * 128;               // 0,128
    int wn = (wave & 3) * 64;                 // 0,64,128,192
    int lrow8 = lane >> 3;
    int gchunk = ((lane & 7) ^ lrow8) * 8;    // pre-swizzled global k-offset (shorts)
    int r16 = lane & 15, quad = lane >> 4;
    int pc0 = ((quad)     ^ (r16 & 7)) * 8;
    int pc1 = ((4 + quad) ^ (r16 & 7)) * 8;

    // staging: wave w owns A rows [32w,32w+32) and B rows [32w,32w+32): 4+4 glds/tile
    const size_t ko = (size_t)ks * GKH + gchunk;
    const unsigned short* ap0 = Aop + (size_t)(bm + wave * 32 +  0 + lrow8) * GK + ko;
    const unsigned short* ap1 = Aop + (size_t)(bm + wave * 32 +  8 + lrow8) * GK + ko;
    const unsigned short* ap2 = Aop + (size_t)(bm + wave * 32 + 16 + lrow8) * GK + ko;
    const unsigned short* ap3 = Aop + (size_t)(bm + wave * 32 + 24 + lrow8) * GK + ko;
    const unsigned short* bp0 = Bop + (size_t)(bn + wave * 32 +  0 + lrow8) * GK + ko;
    const unsigned short* bp1 = Bop + (size_t)(bn + wave * 32 +  8 + lrow8) * GK + ko;
    const unsigned short* bp2 = Bop + (size_t)(bn + wave * 32 + 16 + lrow8) * GK + ko;
    const unsigned short* bp3 = Bop + (size_t)(bn + wave * 32 + 24 + lrow8) * GK + ko;

    f32x4 acc[8][4] = {};

#define STAGE2(s) do { \
    short* la = lds + (s) * BUFS + (wave * 32) * 64; \
    short* lb = lds + (s) * BUFS + 256 * 64 + (wave * 32) * 64; \
    GLDS16(ap0, la);            GLDS16(ap1, la + 8 * 64); \
    GLDS16(ap2, la + 16 * 64);  GLDS16(ap3, la + 24 * 64); \
    GLDS16(bp0, lb);            GLDS16(bp1, lb + 8 * 64); \
    GLDS16(bp2, lb + 16 * 64);  GLDS16(bp3, lb + 24 * 64); \
    ap0 += 64; ap1 += 64; ap2 += 64; ap3 += 64; \
    bp0 += 64; bp1 += 64; bp2 += 64; bp3 += 64; } while (0)

    // prologue: tiles 0,1 into the two buffers; require tile 0 resident, leave tile 1 in flight
    STAGE2(0); STAGE2(1);
    asm volatile("s_waitcnt vmcnt(8)" ::: "memory");
    __builtin_amdgcn_s_barrier();
    asm volatile("" ::: "memory");

    int buf = 0;
#pragma unroll 1
    for (int T = 0; T < NT; ++T) {
        const short* Ab = lds + buf * BUFS;
        const short* Bb = Ab + 256 * 64;
        short8 a0[8], a1[8], b0[4], b1[4];
#pragma unroll
        for (int j = 0; j < 4; ++j) {
            b0[j] = *(const short8*)&Bb[(wn + j * 16 + r16) * 64 + pc0];
            b1[j] = *(const short8*)&Bb[(wn + j * 16 + r16) * 64 + pc1];
        }
        a0[0] = *(const short8*)&Ab[(wm + r16) * 64 + pc0];
        a1[0] = *(const short8*)&Ab[(wm + r16) * 64 + pc1];
#pragma unroll
        for (int i = 0; i < 8; ++i) {
            if (i < 7) {
                a0[i + 1] = *(const short8*)&Ab[(wm + (i + 1) * 16 + r16) * 64 + pc0];
                a1[i + 1] = *(const short8*)&Ab[(wm + (i + 1) * 16 + r16) * 64 + pc1];
                asm volatile("s_waitcnt lgkmcnt(2)" ::: "memory");   // all but newest a-pair done
            } else {
                asm volatile("s_waitcnt lgkmcnt(0)" ::: "memory");
            }
            __builtin_amdgcn_sched_barrier(0);                       // rule 18: pin MFMA below wait
            __builtin_amdgcn_s_setprio(1);
#pragma unroll
            for (int j = 0; j < 4; ++j) {
                acc[i][j] = __builtin_amdgcn_mfma_f32_16x16x32_bf16(a0[i], b0[j], acc[i][j], 0, 0, 0);
                acc[i][j] = __builtin_amdgcn_mfma_f32_16x16x32_bf16(a1[i], b1[j], acc[i][j], 0, 0, 0);
            }
            __builtin_amdgcn_s_setprio(0);
        }
        // tile T+1's loads were issued one full iteration ago -> this drain is ~free
        asm volatile("s_waitcnt vmcnt(0)" ::: "memory");
        __builtin_amdgcn_s_barrier();
        asm volatile("" ::: "memory");
        if (T + 2 < NT) STAGE2(buf);       // overwrite just-freed buffer with tile T+2
        buf ^= 1;
    }
#undef STAGE2

    float* Cout = Cpart + (size_t)ks * K2 * LTOT;
    int col = lane & 15, rq = (lane >> 4) * 4;
#pragma unroll
    for (int i = 0; i < 8; ++i) {
#pragma unroll
        for (int r = 0; r < 4; ++r) {
            int m = bm + wm + i * 16 + rq + r;
#pragma unroll
            for (int j = 0; j < 4; ++j)
                Cout[(size_t)m * LTOT + bn + wn + j * 16 + col] = acc[i][j][r];
        }
    }
}

// ---------------- 9-tap patch stencil, VECTORIZED: thread t owns 16 consecutive cols p0=16t ----------------
__global__ __launch_bounds__(256) void stencil_norm_kernel(
    const float* __restrict__ C, const float* __restrict__ invn,
    float* __restrict__ Sg)
{
    int blk = blockIdx.x;
    int q = ((blk & 7) << 9) | (blk >> 3);   // XCD swizzle: contiguous 512-q per XCD
    int t = threadIdx.x;
    int qy = q >> 6, qx = q & 63;
    int chunk = t >> 2;                      // py (uniform over the 16 cols)
    int lanebase = (t & 3) << 4;             // px of first col
    int p0 = t << 4;

    f32x4 acc[4];
#pragma unroll
    for (int g = 0; g < 4; ++g) { acc[g][0] = acc[g][1] = acc[g][2] = acc[g][3] = 0.f; }

#pragma unroll
    for (int du = -1; du <= 1; ++du) {
        if (qy + du < 0 || qy + du > 63) continue;
        if (chunk + du < 0 || chunk + du > 63) continue;   // py+du (uniform)
#pragma unroll
        for (int dv = -1; dv <= 1; ++dv) {
            if (qx + dv < 0 || qx + dv > 63) continue;
            const float* rowp = C + (size_t)(q + 64 * du + dv) * LTOT + 64 * du + dv + p0;
#pragma unroll
            for (int g = 0; g < 4; ++g) {
                f32x4 lv = ld4u(rowp + 4 * g);
                if (dv == -1 && g == 0 && lanebase == 0)  lv[0] = 0.f;  // px+dv = -1
                if (dv ==  1 && g == 3 && lanebase == 48) lv[3] = 0.f;  // px+dv = 64
                acc[g] += lv;
            }
        }
    }
    float* orow = Sg + (size_t)q * PSTR;
#pragma unroll
    for (int g = 0; g < 4; ++g) {
        f32x4 iv = *(const f32x4*)(invn + p0 + 4 * g);
        *(f32x4*)(orow + p0 + 4 * g) = acc[g] * iv;
    }
    // zero this row's column pads (reads touch cols -1 .. 4099)
    if (t == 0) { orow[-4] = orow[-3] = orow[-2] = orow[-1] = 0.f; }
    else if (t == 1) { orow[4096] = orow[4097] = orow[4098] = orow[4099] = 0.f; }
    // zero guard rows -1 and 4096 (full padded rows)
    if (q == 0) {
        float* gr = Sg - 4 - PSTR;
        for (int k = t; k < PSTR; k += 256) gr[k] = 0.f;
    }
    if (q == 4095) {
        float* gr = Sg - 4 + (size_t)4096 * PSTR;
        for (int k = t; k < PSTR; k += 256) gr[k] = 0.f;
    }
}

// ---------------- fused (fuse2 o fuse1) stencil + row softmax + bf16, VECTORIZED ----------------
__global__ __launch_bounds__(256) void fused_conv_softmax_kernel(
    const float* __restrict__ Sg, const float* __restrict__ mmv,
    unsigned short* __restrict__ S16)
{
    __shared__ float redmax[4];
    __shared__ float redsum[4];
    int blk = blockIdx.x;
    int q = ((blk & 7) << 9) | (blk >> 3);
    int t = threadIdx.x;
    int lane = t & 63, wid = t >> 6;
    int chunk = t >> 2;
    int lanebase = (t & 3) << 4;
    int c0 = t << 4;

    int rbase = ((q & 63) << 6) | (q >> 6);     // swap(q)

    f32x4 sacc[4];
#pragma unroll
    for (int g = 0; g < 4; ++g) { sacc[g][0] = sacc[g][1] = sacc[g][2] = sacc[g][3] = 0.f; }

#pragma unroll
    for (int j = 0; j < 3; ++j) {               // d2 = j-1 (fuse2, flat bounds in swapped space)
        int r2 = rbase + (j - 1);
        if (r2 < 0 || r2 >= LTOT) continue;     // block-uniform
        int rr = ((r2 & 63) << 6) | (r2 >> 6);  // swap(r2)
        int cj = chunk + (j - 1);
        int ccb;
        if (cj < 0)       ccb = 4031 + lanebase;
        else if (cj > 63) ccb = lanebase + 1;
        else              ccb = (cj << 6) + lanebase;
        const float* pr = Sg + (size_t)rr * PSTR + ccb;
#pragma unroll
        for (int g = 0; g < 4; ++g) {
            const float* pg = pr + 4 * g;
            f32x4 lm = ld4u(pg - (PSTR + 1));   // d1 = -1: row rr-1, col cc-1
            f32x4 l0 = ld4u(pg);                // d1 =  0
            f32x4 lp = ld4u(pg + (PSTR + 1));   // d1 = +1
            f32x4 tj = lm + l0 + lp;
            if (j == 0 && g == 0 && t == 0)   tj[0] = 0.f;   // c=0 corner (c2=-1)
            if (j == 2 && g == 3 && t == 255) tj[3] = 0.f;   // c=4095 corner (c2=4096)
            sacc[g] += tj;
        }
    }

    float v[16];
#pragma unroll
    for (int g = 0; g < 4; ++g) {
        f32x4 m4 = *(const f32x4*)(mmv + c0 + 4 * g);
#pragma unroll
        for (int e = 0; e < 4; ++e)
            v[4 * g + e] = sacc[g][e] * m4[e] * SCALE_F;
    }
#pragma unroll
    for (int k = 0; k < 16; ++k) asm volatile("" : "+v"(v[k]));   // pin: no remat of the stencil

    float mx = v[0];
#pragma unroll
    for (int i = 1; i < 16; ++i) mx = fmaxf(mx, v[i]);
#pragma unroll
    for (int o = 32; o; o >>= 1) mx = fmaxf(mx, __shfl_xor(mx, o));
    if (lane == 0) redmax[wid] = mx;
    __syncthreads();
    float gmx = fmaxf(fmaxf(redmax[0], redmax[1]), fmaxf(redmax[2], redmax[3]));

    float s = 0.f;
#pragma unroll
    for (int i = 0; i < 16; ++i) {
        v[i] = __expf(v[i] - gmx);
        s += v[i];
    }
#pragma unroll
    for (int o = 32; o; o >>= 1) s += __shfl_xor(s, o);
    if (lane == 0) redsum[wid] = s;
    __syncthreads();
    float inv = 1.f / (redsum[0] + redsum[1] + redsum[2] + redsum[3]);

    unsigned short* orow = S16 + (size_t)q * LTOT + c0;
    short8 h0, h1;
#pragma unroll
    for (int e = 0; e < 8; ++e) {
        h0[e] = (short)f2bf(v[e]     * inv * mmv[c0 + e]);
        h1[e] = (short)f2bf(v[8 + e] * inv * mmv[c0 + 8 + e]);
    }
    *(short8*)orow = h0;
    *(short8*)(orow + 8) = h1;
}

// ---------------- overlap-add of weighted 4x4 patches (stride 2), /4 ----------------
// C2t is TRANSPOSED and SPLIT-K: two partials [m2][q]; taps contiguous across threads (x->ox).
__global__ void output_kernel(const float* __restrict__ C2t, float* __restrict__ out) {
    const float* __restrict__ P1 = C2t + (size_t)K2 * LTOT;
    int idx = blockIdx.x * blockDim.x + threadIdx.x;   // CC*HH*WW
    int x = idx & 127;
    int y = (idx >> 7) & 127;
    int c = idx >> 14;
    int oylo = max(0, (y - 1) >> 1), oyhi = min(63, (y + 1) >> 1);
    int oxlo = max(0, (x - 1) >> 1), oxhi = min(63, (x + 1) >> 1);
    float s = 0.f;
    for (int oy = oylo; oy <= oyhi; ++oy)
        for (int ox = oxlo; ox <= oxhi; ++ox) {
            int kd = y - 2 * oy + 1;
            int ke = x - 2 * ox + 1;
            size_t off = (size_t)(c * 16 + kd * 4 + ke) * LTOT + oy * 64 + ox;
            s += C2t[off] + P1[off];
        }
    out[idx] = s * 0.25f;
}

extern "C" void kernel_launch(void* const* d_in, const int* in_sizes, int n_in,
                              void* d_out, int out_size, void* d_ws, size_t ws_size,
                              hipStream_t stream) {
    (void)in_sizes; (void)n_in; (void)out_size; (void)ws_size;
    const float* f    = (const float*)d_in[0];
    const float* b    = (const float*)d_in[1];
    const float* mask = (const float*)d_in[2];
    float* out = (float*)d_out;

    const size_t SZ_MAT  = (size_t)LTOT * LTOT * 4;        // 64 MB
    const size_t SZ_SPAD = (size_t)PSTR * 4098 * 4;        // 67.3 MB padded S (guards + col pads)
    const size_t SZ_WR   = (size_t)K2 * LTOT * 2;          // 16 MB
    const size_t SZ_SP   = (size_t)LTOT * K0S * 2;         // 3 MB
    const size_t SZ_V    = (size_t)LTOT * 4;

    auto pad = [](size_t n) { return (n + 255) & ~(size_t)255; };
    char* p = (char*)d_ws;
    auto take = [&](size_t n) -> void* { void* r = (void*)p; p += pad(n); return r; };

    // footprint: 0.25K guard + 64 + 67.3 + 16 (single W) + 4*3 + small ~= 160 MB (< proven 172)
    take(256);                                     // guard: stencil corner reads C[-1]
    float* Buf1 = (float*)take(SZ_MAT);            // Cpix -> S16 (lower 32 MB)
    float* Spad = (float*)take(SZ_SPAD);           // padded S -> C2t partials (lower 64 MB)
    unsigned short* W = (unsigned short*)take(SZ_WR);   // per-batch raw patches (im2col in loop)
    unsigned short* Bsp0 = (unsigned short*)take(SZ_SP);
    unsigned short* Fsp0 = (unsigned short*)take(SZ_SP);
    unsigned short* Bsp1 = (unsigned short*)take(SZ_SP);
    unsigned short* Fsp1 = (unsigned short*)take(SZ_SP);
    float* ssq0 = (float*)take(SZ_V);  float* ssq1 = (float*)take(SZ_V);
    float* invn0 = (float*)take(SZ_V); float* invn1 = (float*)take(SZ_V);
    float* mmv0 = (float*)take(SZ_V);  float* mmv1 = (float*)take(SZ_V);

    const float* f0 = f,  *b0 = b;
    const float* f1 = f + IMG, *b1 = b + IMG;

    float* Sg = Spad + PSTR + 4;                   // padded S row 0, col 0
    unsigned short* S16 = (unsigned short*)Buf1;   // 32 MB, after Cpix dead
    float* C2t = Spad;                             // 2 x 32 MB partials, after padded S dead

    // ---- merged prep (both batches); ssq fused into the b split passes ----
    Prep4 P{{b0, f0, b1, f1}, {Bsp0, Fsp0, Bsp1, Fsp1},
            {ssq0, nullptr, ssq1, nullptr}, {1, 0, 1, 0}};
    split_ds_kernel<<<dim3(LTOT, 1, 4), 128, 0, stream>>>(P);
    PtrN2 nm{{ssq0, ssq1}, {invn0, invn1}, {mmv0, mmv1}};
    norm_mm_kernel<<<dim3(16, 1, 2), 256, 0, stream>>>(nm, mask);

    // ---- per-batch pipeline ----
    for (int bi = 0; bi < 2; ++bi) {
        const unsigned short* Fsp = bi ? Fsp1 : Fsp0;
        const unsigned short* Bsp = bi ? Bsp1 : Bsp0;
        const float* invn = bi ? invn1 : invn0;
        const float* mmv  = bi ? mmv1 : mmv0;

        // raw 4x4 patches for this batch only (W reused across batches)
        PtrR2 rw{{bi ? b1 : b0, nullptr}, {W, nullptr}};
        im2col_rawt_kernel<<<dim3((size_t)K2 * LTOT / 256, 1, 1), 256, 0, stream>>>(rw);

        // Cpix[q][p] = sum_c fd[c][q]*bd[c][p]   (split-concat fp32-accurate, K=384)
        gemm_mfma<<<dim3(32, 32), 256, 0, stream>>>(Fsp, Bsp, Buf1, LTOT, LTOT, K0S);

        // patch inner products: 9-tap diagonal stencil + invn column scale -> padded S
        stencil_norm_kernel<<<LTOT, 256, 0, stream>>>(Buf1, invn, Sg);

        // fused (fuse2 o fuse1) + softmax + bf16 cast  (Cpix dead -> S16 in Buf1 lower half)
        fused_conv_softmax_kernel<<<LTOT, 256, 0, stream>>>(Sg, mmv, S16);

        // TRANSPOSED GEMM2 (R5 ring-2 + XCD panel grouping): C2t_ks[m2][q] = sum_p W[m2][p]*S16[q][p]
        gemm_k2<<<256, 512, 0, stream>>>(W, S16, C2t);

        output_kernel<<<CC * HH * WW / 256, 256, 0, stream>>>(C2t, out + (size_t)bi * IMG);
    }
}

// Round 8
// 510.947 us; speedup vs baseline: 1.0270x; 1.0123x over previous
//
#include <hip/hip_runtime.h>

#define CC 128
#define HH 128
#define WW 128
#define DH 64
#define DW 64
#define LTOT 4096          // DH*DW patches / fg positions
#define K0S 384            // 3*128 split-concat K for the pixel-pair GEMM
#define K2 2048            // CC*4*4
#define GK 4096            // GEMM2 full K
#define GKH 2048           // GEMM2 half K (split-K by 2)
#define SCALE_F 10.0f
#define IMG ((size_t)CC * HH * WW)
#define PSTR 4104          // padded S row stride (floats): 4 pad | 4096 | 4 pad; %4==0 keeps 16B align

typedef __attribute__((ext_vector_type(8))) short short8;
typedef __attribute__((ext_vector_type(4))) float f32x4;

// ---- pointer-pack structs (batch-merged prep via blockIdx.z) ----
struct Prep4 { const float* src[4]; unsigned short* dst[4]; float* ssq[4]; int lo[4]; };
struct PtrN2 { const float* ssq[2]; float* invn[2]; float* mmv[2]; };
struct PtrR2 { const float* src[2]; unsigned short* dst[2]; };

// ---- bf16 helpers (RNE) ----
__device__ __forceinline__ unsigned short f2bf(float x) {
    union { float f; unsigned u; } v; v.f = x;
    unsigned r = v.u + 0x7fffu + ((v.u >> 16) & 1u);
    return (unsigned short)(r >> 16);
}
__device__ __forceinline__ float bf2f(unsigned short b) {
    union { unsigned u; float f; } v; v.u = ((unsigned)b) << 16;
    return v.f;
}

// unaligned (4B-aligned) float4 load
__device__ __forceinline__ f32x4 ld4u(const float* p) {
    f32x4 r; __builtin_memcpy(&r, p, 16); return r;
}

#define GLDS16(g, l) __builtin_amdgcn_global_load_lds( \
    (const __attribute__((address_space(1))) void*)(g), \
    (__attribute__((address_space(3))) void*)(l), 16, 0, 0)

// ---------------- downsample (::2) + fp32->bf16 split + (for b) fused ssq reduce ----------------
// b gets [hi, lo, hi], f gets [hi, hi, lo]  =>  products sum to hi*hi + lo*hi + hi*lo
__global__ __launch_bounds__(128) void split_ds_kernel(Prep4 P) {
    __shared__ float partial[2];
    int z = blockIdx.z;
    const float* __restrict__ src = P.src[z];
    unsigned short* __restrict__ dst = P.dst[z];
    int lo_in_seg1 = P.lo[z];
    int n = blockIdx.x;          // 4096 pixels
    int c = threadIdx.x;         // 128 channels
    int ny = n >> 6, nx = n & 63;
    float v = src[((size_t)c * HH + 2 * ny) * WW + 2 * nx];
    unsigned short hi = f2bf(v);
    unsigned short lo = f2bf(v - bf2f(hi));
    unsigned short* drow = dst + (size_t)n * K0S;
    drow[c]       = hi;
    drow[128 + c] = lo_in_seg1 ? lo : hi;
    drow[256 + c] = lo_in_seg1 ? hi : lo;

    float* ssq = P.ssq[z];
    if (ssq) {                   // b images only: per-pixel channel sum of squares
        float s2 = v * v;
#pragma unroll
        for (int o = 32; o; o >>= 1) s2 += __shfl_xor(s2, o);
        if ((threadIdx.x & 63) == 0) partial[threadIdx.x >> 6] = s2;
        __syncthreads();
        if (threadIdx.x == 0) ssq[n] = partial[0] + partial[1];
    }
}

// ---------------- raw 4x4 stride-2 patches of full-res b, transposed: dst[m2][p] bf16 ----------------
// R8: old version = 1 scalar stride-2 fp32 read/thread (50% bus waste, 8.4M scalar loads).
// New: thread owns a px-PAIR of one (c,kd,ke) plane. Interior (u in 1..30): one unaligned
// f32x4 covers both taps (xx0 and xx0+2); consecutive u -> xx0 stride 4 -> fully contiguous
// coverage, 4x fewer load instrs. Edge threads (u=0,31) keep scalar bounds-checked path
// (also avoids OOB reads before/after the image). ushort2 store. Values identical.
__global__ __launch_bounds__(256) void im2col_rawt_kernel(PtrR2 P) {
    int z = blockIdx.z;
    const float* __restrict__ src = P.src[z];
    unsigned short* __restrict__ dst = P.dst[z];
    int idx = blockIdx.x * 256 + threadIdx.x;     // m*2048 + py*32 + u
    int u  = idx & 31;                             // px pair index: px0 = 2u
    int py = (idx >> 5) & 63;
    int m  = idx >> 11;                            // (c,kd,ke)
    int ke = m & 3, kd = (m >> 2) & 3, c = m >> 4;
    int yy = 2 * py - 1 + kd;
    int xx0 = 4 * u - 1 + ke;                      // xx for px0; px1 uses xx0+2
    unsigned short o0 = 0, o1 = 0;
    if (yy >= 0 && yy < HH) {
        const float* row = src + ((size_t)c * HH + yy) * WW;
        if (u == 0 || u == 31) {                   // edges: scalar, bounds-checked
            if (xx0 >= 0 && xx0 < WW)         o0 = f2bf(row[xx0]);
            if (xx0 + 2 >= 0 && xx0 + 2 < WW) o1 = f2bf(row[xx0 + 2]);
        } else {                                   // interior: xx0 in [3,122], xx0+3 <= 125
            f32x4 w = ld4u(row + xx0);
            o0 = f2bf(w[0]); o1 = f2bf(w[2]);
        }
    }
    unsigned short* dp = dst + (size_t)m * LTOT + py * 64 + 2 * u;
    dp[0] = o0; dp[1] = o1;
}

// ---------------- patch inverse norm + mask gate ----------------
__global__ void norm_mm_kernel(PtrN2 P, const float* __restrict__ mask) {
    int z = blockIdx.z;
    const float* __restrict__ ssq = P.ssq[z];
    float* __restrict__ inv_norm = P.invn[z];
    float* __restrict__ mmv = P.mmv[z];
    int p = blockIdx.x * blockDim.x + threadIdx.x;     // 4096
    int px = p & 63, py = p >> 6;
    float s = 0.f, ms = 0.f;
    for (int di = -1; di <= 1; ++di)
        for (int dj = -1; dj <= 1; ++dj) {
            int y = py + di, x = px + dj;
            if (y >= 0 && y < DH && x >= 0 && x < DW) {
                s += ssq[y * 64 + x];
                ms += mask[(size_t)(2 * y) * WW + 2 * x];
            }
        }
    float n = sqrtf(s);
    if (n < 1e-4f) n = 1e-4f;
    inv_norm[p] = 1.f / n;
    mmv[p] = (ms == 0.f) ? 1.f : 0.f;
}

// ---------------- bf16 MFMA GEMM, BK=64, hoisted running pointers, XOR swizzle ----------------
// (kept for GEMM1: M=N=4096, K=384 — short-K, 1024 blocks; write-bound, 4 blocks/CU overlap)
__global__ __launch_bounds__(256) void gemm_mfma(
    const unsigned short* __restrict__ Aop, const unsigned short* __restrict__ Bop,
    float* __restrict__ C, int M, int N, int K)
{
    __shared__ short As[128 * 64];
    __shared__ short Bs[128 * 64];
    int tid = threadIdx.x;
    int wave = tid >> 6, lane = tid & 63;
    int wm = (wave >> 1) * 64;
    int wn = (wave & 1) * 64;
    int bm = blockIdx.y * 128, bn = blockIdx.x * 128;

    int rowS = wave * 32;              // wave stages rows [rowS, rowS+32)
    int lrow8 = lane >> 3;             // 0..7 (row within 8-row staging group)
    int gchunk = ((lane & 7) ^ lrow8) * 8;   // swizzled global k-offset (shorts)

    f32x4 acc[4][4] = {};

    int quad = lane >> 4;              // 0..3
    int r16 = lane & 15;
    int pc0 = ((quad)     ^ (r16 & 7)) * 8;  // physical chunk of k-slab 0
    int pc1 = ((4 + quad) ^ (r16 & 7)) * 8;  // physical chunk of k-slab 1

    const unsigned short* ap0 = Aop + (size_t)(bm + rowS +  0 + lrow8) * K + gchunk;
    const unsigned short* ap1 = Aop + (size_t)(bm + rowS +  8 + lrow8) * K + gchunk;
    const unsigned short* ap2 = Aop + (size_t)(bm + rowS + 16 + lrow8) * K + gchunk;
    const unsigned short* ap3 = Aop + (size_t)(bm + rowS + 24 + lrow8) * K + gchunk;
    const unsigned short* bp0 = Bop + (size_t)(bn + rowS +  0 + lrow8) * K + gchunk;
    const unsigned short* bp1 = Bop + (size_t)(bn + rowS +  8 + lrow8) * K + gchunk;
    const unsigned short* bp2 = Bop + (size_t)(bn + rowS + 16 + lrow8) * K + gchunk;
    const unsigned short* bp3 = Bop + (size_t)(bn + rowS + 24 + lrow8) * K + gchunk;
    short* lA = As + rowS * 64;        // wave-uniform LDS bases
    short* lB = Bs + rowS * 64;

    for (int k0 = 0; k0 < K; k0 += 64) {
        GLDS16(ap0, lA);            GLDS16(ap1, lA + 8 * 64);
        GLDS16(ap2, lA + 16 * 64);  GLDS16(ap3, lA + 24 * 64);
        GLDS16(bp0, lB);            GLDS16(bp1, lB + 8 * 64);
        GLDS16(bp2, lB + 16 * 64);  GLDS16(bp3, lB + 24 * 64);
        ap0 += 64; ap1 += 64; ap2 += 64; ap3 += 64;
        bp0 += 64; bp1 += 64; bp2 += 64; bp3 += 64;
        __syncthreads();

        short8 a0[4], b0[4], a1[4], b1[4];
#pragma unroll
        for (int i = 0; i < 4; ++i) {
            a0[i] = *(const short8*)&As[(wm + i * 16 + r16) * 64 + pc0];
            b0[i] = *(const short8*)&Bs[(wn + i * 16 + r16) * 64 + pc0];
            a1[i] = *(const short8*)&As[(wm + i * 16 + r16) * 64 + pc1];
            b1[i] = *(const short8*)&Bs[(wn + i * 16 + r16) * 64 + pc1];
        }
#pragma unroll
        for (int i = 0; i < 4; ++i)
#pragma unroll
            for (int j = 0; j < 4; ++j) {
                acc[i][j] = __builtin_amdgcn_mfma_f32_16x16x32_bf16(a0[i], b0[j], acc[i][j], 0, 0, 0);
                acc[i][j] = __builtin_amdgcn_mfma_f32_16x16x32_bf16(a1[i], b1[j], acc[i][j], 0, 0, 0);
            }
        __syncthreads();
    }

    int col = lane & 15, rq = (lane >> 4) * 4;
#pragma unroll
    for (int i = 0; i < 4; ++i) {
#pragma unroll
        for (int r = 0; r < 4; ++r) {
            int m = bm + wm + i * 16 + rq + r;
#pragma unroll
            for (int j = 0; j < 4; ++j)
                C[(size_t)m * N + bn + wn + j * 16 + col] = acc[i][j][r];
        }
    }
}

// ---------------- GEMM2: 256x256, split-K/2, ring-2 counted vmcnt + XCD panel swizzle + b-hoist ----------------
// R8: R5 body + hoisted B-frag reads. Old: each iter's first MFMA waited on all 8 B-reads
// issued at iter top (~300 cyc exposed, both waves/SIMD barrier-locked). Now: B-frags of
// tile T+1 are read right after iter T's vmcnt(0)+barrier (tile T+1 block-wide resident;
// reads hit slot buf^1 while STAGE writes slot buf — disjoint). Rolling lgkmcnt(2) at the
// a-pair ladder still retires them before the first MFMA. XCD grouping (R7, FETCH 82->49MB):
// flat 256-block grid, all 8 bm-blocks of one (bn,ks) B-panel share an XCD.
__global__ __launch_bounds__(512, 2) void gemm_k2(
    const unsigned short* __restrict__ Aop, const unsigned short* __restrict__ Bop,
    float* __restrict__ Cpart)
{
    constexpr int NT = 32;                    // GKH / 64
    constexpr int BUFS = 512 * 64;            // shorts per ring slot (64 KB: A 256 rows + B 256 rows)
    __shared__ short lds[2 * BUFS];           // 128 KB
    int flat = blockIdx.x;
    int xcd  = flat & 7;
    int slot = (flat >> 3) & 3;
    int bmId = flat >> 5;                     // 0..7
    int P    = slot * 8 + xcd;                // 0..31
    int bnId = P >> 1;                        // 0..15
    int ks   = P & 1;                         // K half
    int bm = bmId * 256, bn = bnId * 256;

    int tid = threadIdx.x;
    int wave = tid >> 6, lane = tid & 63;
    int wm = (wave >> 2) * 128;               // 0,128
    int wn = (wave & 3) * 64;                 // 0,64,128,192
    int lrow8 = lane >> 3;
    int gchunk = ((lane & 7) ^ lrow8) * 8;    // pre-swizzled global k-offset (shorts)
    int r16 = lane & 15, quad = lane >> 4;
    int pc0 = ((quad)     ^ (r16 & 7)) * 8;
    int pc1 = ((4 + quad) ^ (r16 & 7)) * 8;

    // staging: wave w owns A rows [32w,32w+32) and B rows [32w,32w+32): 4+4 glds/tile
    const size_t ko = (size_t)ks * GKH + gchunk;
    const unsigned short* ap0 = Aop + (size_t)(bm + wave * 32 +  0 + lrow8) * GK + ko;
    const unsigned short* ap1 = Aop + (size_t)(bm + wave * 32 +  8 + lrow8) * GK + ko;
    const unsigned short* ap2 = Aop + (size_t)(bm + wave * 32 + 16 + lrow8) * GK + ko;
    const unsigned short* ap3 = Aop + (size_t)(bm + wave * 32 + 24 + lrow8) * GK + ko;
    const unsigned short* bp0 = Bop + (size_t)(bn + wave * 32 +  0 + lrow8) * GK + ko;
    const unsigned short* bp1 = Bop + (size_t)(bn + wave * 32 +  8 + lrow8) * GK + ko;
    const unsigned short* bp2 = Bop + (size_t)(bn + wave * 32 + 16 + lrow8) * GK + ko;
    const unsigned short* bp3 = Bop + (size_t)(bn + wave * 32 + 24 + lrow8) * GK + ko;

    f32x4 acc[8][4] = {};

#define STAGE2(s) do { \
    short* la = lds + (s) * BUFS + (wave * 32) * 64; \
    short* lb = lds + (s) * BUFS + 256 * 64 + (wave * 32) * 64; \
    GLDS16(ap0, la);            GLDS16(ap1, la + 8 * 64); \
    GLDS16(ap2, la + 16 * 64);  GLDS16(ap3, la + 24 * 64); \
    GLDS16(bp0, lb);            GLDS16(bp1, lb + 8 * 64); \
    GLDS16(bp2, lb + 16 * 64);  GLDS16(bp3, lb + 24 * 64); \
    ap0 += 64; ap1 += 64; ap2 += 64; ap3 += 64; \
    bp0 += 64; bp1 += 64; bp2 += 64; bp3 += 64; } while (0)

    // prologue: tiles 0,1 into the two buffers; require tile 0 resident, leave tile 1 in flight
    STAGE2(0); STAGE2(1);
    asm volatile("s_waitcnt vmcnt(8)" ::: "memory");
    __builtin_amdgcn_s_barrier();
    asm volatile("" ::: "memory");

    short8 b0[4], b1[4];
    {   // B-frags of tile 0 (resident)
        const short* Bb = lds + 256 * 64;
#pragma unroll
        for (int j = 0; j < 4; ++j) {
            b0[j] = *(const short8*)&Bb[(wn + j * 16 + r16) * 64 + pc0];
            b1[j] = *(const short8*)&Bb[(wn + j * 16 + r16) * 64 + pc1];
        }
    }

    int buf = 0;
#pragma unroll 1
    for (int T = 0; T < NT; ++T) {
        const short* Ab = lds + buf * BUFS;
        short8 a0[8], a1[8];
        a0[0] = *(const short8*)&Ab[(wm + r16) * 64 + pc0];
        a1[0] = *(const short8*)&Ab[(wm + r16) * 64 + pc1];
#pragma unroll
        for (int i = 0; i < 8; ++i) {
            if (i < 7) {
                a0[i + 1] = *(const short8*)&Ab[(wm + (i + 1) * 16 + r16) * 64 + pc0];
                a1[i + 1] = *(const short8*)&Ab[(wm + (i + 1) * 16 + r16) * 64 + pc1];
                asm volatile("s_waitcnt lgkmcnt(2)" ::: "memory");   // all but newest a-pair done
            } else {
                asm volatile("s_waitcnt lgkmcnt(0)" ::: "memory");
            }
            __builtin_amdgcn_sched_barrier(0);                       // rule 18: pin MFMA below wait
            __builtin_amdgcn_s_setprio(1);
#pragma unroll
            for (int j = 0; j < 4; ++j) {
                acc[i][j] = __builtin_amdgcn_mfma_f32_16x16x32_bf16(a0[i], b0[j], acc[i][j], 0, 0, 0);
                acc[i][j] = __builtin_amdgcn_mfma_f32_16x16x32_bf16(a1[i], b1[j], acc[i][j], 0, 0, 0);
            }
            __builtin_amdgcn_s_setprio(0);
        }
        // tile T+1's loads were issued one full iteration ago -> this drain is ~free
        asm volatile("s_waitcnt vmcnt(0)" ::: "memory");
        __builtin_amdgcn_s_barrier();
        asm volatile("" ::: "memory");
        if (T + 2 < NT) STAGE2(buf);       // overwrite just-freed buffer with tile T+2
        if (T + 1 < NT) {                  // hoisted: B-frags of tile T+1 from the other slot
            const short* Bn = lds + (buf ^ 1) * BUFS + 256 * 64;
#pragma unroll
            for (int j = 0; j < 4; ++j) {
                b0[j] = *(const short8*)&Bn[(wn + j * 16 + r16) * 64 + pc0];
                b1[j] = *(const short8*)&Bn[(wn + j * 16 + r16) * 64 + pc1];
            }
        }
        buf ^= 1;
    }
#undef STAGE2

    float* Cout = Cpart + (size_t)ks * K2 * LTOT;
    int col = lane & 15, rq = (lane >> 4) * 4;
#pragma unroll
    for (int i = 0; i < 8; ++i) {
#pragma unroll
        for (int r = 0; r < 4; ++r) {
            int m = bm + wm + i * 16 + rq + r;
#pragma unroll
            for (int j = 0; j < 4; ++j)
                Cout[(size_t)m * LTOT + bn + wn + j * 16 + col] = acc[i][j][r];
        }
    }
}

// ---------------- 9-tap patch stencil, VECTORIZED: thread t owns 16 consecutive cols p0=16t ----------------
__global__ __launch_bounds__(256) void stencil_norm_kernel(
    const float* __restrict__ C, const float* __restrict__ invn,
    float* __restrict__ Sg)
{
    int blk = blockIdx.x;
    int q = ((blk & 7) << 9) | (blk >> 3);   // XCD swizzle: contiguous 512-q per XCD
    int t = threadIdx.x;
    int qy = q >> 6, qx = q & 63;
    int chunk = t >> 2;                      // py (uniform over the 16 cols)
    int lanebase = (t & 3) << 4;             // px of first col
    int p0 = t << 4;

    f32x4 acc[4];
#pragma unroll
    for (int g = 0; g < 4; ++g) { acc[g][0] = acc[g][1] = acc[g][2] = acc[g][3] = 0.f; }

#pragma unroll
    for (int du = -1; du <= 1; ++du) {
        if (qy + du < 0 || qy + du > 63) continue;
        if (chunk + du < 0 || chunk + du > 63) continue;   // py+du (uniform)
#pragma unroll
        for (int dv = -1; dv <= 1; ++dv) {
            if (qx + dv < 0 || qx + dv > 63) continue;
            const float* rowp = C + (size_t)(q + 64 * du + dv) * LTOT + 64 * du + dv + p0;
#pragma unroll
            for (int g = 0; g < 4; ++g) {
                f32x4 lv = ld4u(rowp + 4 * g);
                if (dv == -1 && g == 0 && lanebase == 0)  lv[0] = 0.f;  // px+dv = -1
                if (dv ==  1 && g == 3 && lanebase == 48) lv[3] = 0.f;  // px+dv = 64
                acc[g] += lv;
            }
        }
    }
    float* orow = Sg + (size_t)q * PSTR;
#pragma unroll
    for (int g = 0; g < 4; ++g) {
        f32x4 iv = *(const f32x4*)(invn + p0 + 4 * g);
        *(f32x4*)(orow + p0 + 4 * g) = acc[g] * iv;
    }
    // zero this row's column pads (reads touch cols -1 .. 4099)
    if (t == 0) { orow[-4] = orow[-3] = orow[-2] = orow[-1] = 0.f; }
    else if (t == 1) { orow[4096] = orow[4097] = orow[4098] = orow[4099] = 0.f; }
    // zero guard rows -1 and 4096 (full padded rows)
    if (q == 0) {
        float* gr = Sg - 4 - PSTR;
        for (int k = t; k < PSTR; k += 256) gr[k] = 0.f;
    }
    if (q == 4095) {
        float* gr = Sg - 4 + (size_t)4096 * PSTR;
        for (int k = t; k < PSTR; k += 256) gr[k] = 0.f;
    }
}

// ---------------- fused (fuse2 o fuse1) stencil + row softmax + bf16, VECTORIZED ----------------
__global__ __launch_bounds__(256) void fused_conv_softmax_kernel(
    const float* __restrict__ Sg, const float* __restrict__ mmv,
    unsigned short* __restrict__ S16)
{
    __shared__ float redmax[4];
    __shared__ float redsum[4];
    int blk = blockIdx.x;
    int q = ((blk & 7) << 9) | (blk >> 3);
    int t = threadIdx.x;
    int lane = t & 63, wid = t >> 6;
    int chunk = t >> 2;
    int lanebase = (t & 3) << 4;
    int c0 = t << 4;

    int rbase = ((q & 63) << 6) | (q >> 6);     // swap(q)

    f32x4 sacc[4];
#pragma unroll
    for (int g = 0; g < 4; ++g) { sacc[g][0] = sacc[g][1] = sacc[g][2] = sacc[g][3] = 0.f; }

#pragma unroll
    for (int j = 0; j < 3; ++j) {               // d2 = j-1 (fuse2, flat bounds in swapped space)
        int r2 = rbase + (j - 1);
        if (r2 < 0 || r2 >= LTOT) continue;     // block-uniform
        int rr = ((r2 & 63) << 6) | (r2 >> 6);  // swap(r2)
        int cj = chunk + (j - 1);
        int ccb;
        if (cj < 0)       ccb = 4031 + lanebase;
        else if (cj > 63) ccb = lanebase + 1;
        else              ccb = (cj << 6) + lanebase;
        const float* pr = Sg + (size_t)rr * PSTR + ccb;
#pragma unroll
        for (int g = 0; g < 4; ++g) {
            const float* pg = pr + 4 * g;
            f32x4 lm = ld4u(pg - (PSTR + 1));   // d1 = -1: row rr-1, col cc-1
            f32x4 l0 = ld4u(pg);                // d1 =  0
            f32x4 lp = ld4u(pg + (PSTR + 1));   // d1 = +1
            f32x4 tj = lm + l0 + lp;
            if (j == 0 && g == 0 && t == 0)   tj[0] = 0.f;   // c=0 corner (c2=-1)
            if (j == 2 && g == 3 && t == 255) tj[3] = 0.f;   // c=4095 corner (c2=4096)
            sacc[g] += tj;
        }
    }

    float v[16];
#pragma unroll
    for (int g = 0; g < 4; ++g) {
        f32x4 m4 = *(const f32x4*)(mmv + c0 + 4 * g);
#pragma unroll
        for (int e = 0; e < 4; ++e)
            v[4 * g + e] = sacc[g][e] * m4[e] * SCALE_F;
    }
#pragma unroll
    for (int k = 0; k < 16; ++k) asm volatile("" : "+v"(v[k]));   // pin: no remat of the stencil

    float mx = v[0];
#pragma unroll
    for (int i = 1; i < 16; ++i) mx = fmaxf(mx, v[i]);
#pragma unroll
    for (int o = 32; o; o >>= 1) mx = fmaxf(mx, __shfl_xor(mx, o));
    if (lane == 0) redmax[wid] = mx;
    __syncthreads();
    float gmx = fmaxf(fmaxf(redmax[0], redmax[1]), fmaxf(redmax[2], redmax[3]));

    float s = 0.f;
#pragma unroll
    for (int i = 0; i < 16; ++i) {
        v[i] = __expf(v[i] - gmx);
        s += v[i];
    }
#pragma unroll
    for (int o = 32; o; o >>= 1) s += __shfl_xor(s, o);
    if (lane == 0) redsum[wid] = s;
    __syncthreads();
    float inv = 1.f / (redsum[0] + redsum[1] + redsum[2] + redsum[3]);

    unsigned short* orow = S16 + (size_t)q * LTOT + c0;
    short8 h0, h1;
#pragma unroll
    for (int e = 0; e < 8; ++e) {
        h0[e] = (short)f2bf(v[e]     * inv * mmv[c0 + e]);
        h1[e] = (short)f2bf(v[8 + e] * inv * mmv[c0 + 8 + e]);
    }
    *(short8*)orow = h0;
    *(short8*)(orow + 8) = h1;
}

// ---------------- overlap-add of weighted 4x4 patches (stride 2), /4 ----------------
// C2t is TRANSPOSED and SPLIT-K: two partials [m2][q]; taps contiguous across threads (x->ox).
__global__ void output_kernel(const float* __restrict__ C2t, float* __restrict__ out) {
    const float* __restrict__ P1 = C2t + (size_t)K2 * LTOT;
    int idx = blockIdx.x * blockDim.x + threadIdx.x;   // CC*HH*WW
    int x = idx & 127;
    int y = (idx >> 7) & 127;
    int c = idx >> 14;
    int oylo = max(0, (y - 1) >> 1), oyhi = min(63, (y + 1) >> 1);
    int oxlo = max(0, (x - 1) >> 1), oxhi = min(63, (x + 1) >> 1);
    float s = 0.f;
    for (int oy = oylo; oy <= oyhi; ++oy)
        for (int ox = oxlo; ox <= oxhi; ++ox) {
            int kd = y - 2 * oy + 1;
            int ke = x - 2 * ox + 1;
            size_t off = (size_t)(c * 16 + kd * 4 + ke) * LTOT + oy * 64 + ox;
            s += C2t[off] + P1[off];
        }
    out[idx] = s * 0.25f;
}

extern "C" void kernel_launch(void* const* d_in, const int* in_sizes, int n_in,
                              void* d_out, int out_size, void* d_ws, size_t ws_size,
                              hipStream_t stream) {
    (void)in_sizes; (void)n_in; (void)out_size; (void)ws_size;
    const float* f    = (const float*)d_in[0];
    const float* b    = (const float*)d_in[1];
    const float* mask = (const float*)d_in[2];
    float* out = (float*)d_out;

    const size_t SZ_MAT  = (size_t)LTOT * LTOT * 4;        // 64 MB
    const size_t SZ_SPAD = (size_t)PSTR * 4098 * 4;        // 67.3 MB padded S (guards + col pads)
    const size_t SZ_WR   = (size_t)K2 * LTOT * 2;          // 16 MB
    const size_t SZ_SP   = (size_t)LTOT * K0S * 2;         // 3 MB
    const size_t SZ_V    = (size_t)LTOT * 4;

    auto pad = [](size_t n) { return (n + 255) & ~(size_t)255; };
    char* p = (char*)d_ws;
    auto take = [&](size_t n) -> void* { void* r = (void*)p; p += pad(n); return r; };

    // footprint: 0.25K guard + 64 + 67.3 + 16 (single W) + 4*3 + small ~= 160 MB (< proven 172)
    take(256);                                     // guard: stencil corner reads C[-1]
    float* Buf1 = (float*)take(SZ_MAT);            // Cpix -> S16 (lower 32 MB)
    float* Spad = (float*)take(SZ_SPAD);           // padded S -> C2t partials (lower 64 MB)
    unsigned short* W = (unsigned short*)take(SZ_WR);   // per-batch raw patches (im2col in loop)
    unsigned short* Bsp0 = (unsigned short*)take(SZ_SP);
    unsigned short* Fsp0 = (unsigned short*)take(SZ_SP);
    unsigned short* Bsp1 = (unsigned short*)take(SZ_SP);
    unsigned short* Fsp1 = (unsigned short*)take(SZ_SP);
    float* ssq0 = (float*)take(SZ_V);  float* ssq1 = (float*)take(SZ_V);
    float* invn0 = (float*)take(SZ_V); float* invn1 = (float*)take(SZ_V);
    float* mmv0 = (float*)take(SZ_V);  float* mmv1 = (float*)take(SZ_V);

    const float* f0 = f,  *b0 = b;
    const float* f1 = f + IMG, *b1 = b + IMG;

    float* Sg = Spad + PSTR + 4;                   // padded S row 0, col 0
    unsigned short* S16 = (unsigned short*)Buf1;   // 32 MB, after Cpix dead
    float* C2t = Spad;                             // 2 x 32 MB partials, after padded S dead

    // ---- merged prep (both batches); ssq fused into the b split passes ----
    Prep4 P{{b0, f0, b1, f1}, {Bsp0, Fsp0, Bsp1, Fsp1},
            {ssq0, nullptr, ssq1, nullptr}, {1, 0, 1, 0}};
    split_ds_kernel<<<dim3(LTOT, 1, 4), 128, 0, stream>>>(P);
    PtrN2 nm{{ssq0, ssq1}, {invn0, invn1}, {mmv0, mmv1}};
    norm_mm_kernel<<<dim3(16, 1, 2), 256, 0, stream>>>(nm, mask);

    // ---- per-batch pipeline ----
    for (int bi = 0; bi < 2; ++bi) {
        const unsigned short* Fsp = bi ? Fsp1 : Fsp0;
        const unsigned short* Bsp = bi ? Bsp1 : Bsp0;
        const float* invn = bi ? invn1 : invn0;
        const float* mmv  = bi ? mmv1 : mmv0;

        // raw 4x4 patches for this batch only (W reused across batches); px-pair threads
        PtrR2 rw{{bi ? b1 : b0, nullptr}, {W, nullptr}};
        im2col_rawt_kernel<<<dim3((size_t)K2 * LTOT / 2 / 256, 1, 1), 256, 0, stream>>>(rw);

        // Cpix[q][p] = sum_c fd[c][q]*bd[c][p]   (split-concat fp32-accurate, K=384)
        gemm_mfma<<<dim3(32, 32), 256, 0, stream>>>(Fsp, Bsp, Buf1, LTOT, LTOT, K0S);

        // patch inner products: 9-tap diagonal stencil + invn column scale -> padded S
        stencil_norm_kernel<<<LTOT, 256, 0, stream>>>(Buf1, invn, Sg);

        // fused (fuse2 o fuse1) + softmax + bf16 cast  (Cpix dead -> S16 in Buf1 lower half)
        fused_conv_softmax_kernel<<<LTOT, 256, 0, stream>>>(Sg, mmv, S16);

        // TRANSPOSED GEMM2 (ring-2 + XCD grouping + b-hoist): C2t_ks[m2][q] = sum_p W[m2][p]*S16[q][p]
        gemm_k2<<<256, 512, 0, stream>>>(W, S16, C2t);

        output_kernel<<<CC * HH * WW / 256, 256, 0, stream>>>(C2t, out + (size_t)bi * IMG);
    }
}